// Round 9
// baseline (742.068 us; speedup 1.0000x reference)
//
#include <hip/hip_runtime.h>
#include <hip/hip_bf16.h>
#include <stdint.h>

// MResConv on MI355X: two MeshCNN convs as bf16 MFMA GEMMs + fused BN stats.
// R6: BN=128 tile (940 blocks) halves W L2 traffic (1.23GB -> 600MB conv1);
//     wave = 32ch x 128e (16 acc frags, full W dedup), BC=32/KCH=160,
//     depth-2 W register pipeline, same barrier-safe STAGE placement.
// ws layout (bytes):
//   xT   [B][E][128] bf16      @ 0           (30,720,000)
//   Wf0  [20][256][32] bf16    @ 30720000    (327,680)
//   Wf1  [40][256][32] bf16    @ 31047680    (655,360)
//   x1   frag-blocked bf16     @ 31703040    (61,603,840)
//   rT   [B][E][256] bf16      @ 93306880    (61,440,000)
//   part [940][2][256] f32     @ 154746880   (1,925,120)
//   ss   [2][256] f32          @ 156672000   (2,048)
//   bias [256] f32             @ 156674048   (1,024)

#define BB 4
#define CIN 128
#define COUT 256
#define EE 30000
#define BN 128
#define NT 235              // ceil(30000/128)
#define BC 32
#define KCH 160             // 5*BC K-values per chunk
#define PITCH 164           // 328B rows: stride 82 dw == 18 mod 32 -> bank-clean
#define NBLK (NT * BB)      // 940
#define GRID1 944           // swizzled 1D grid for conv kernels (118*8)

typedef __attribute__((ext_vector_type(8))) short bf16x8;
typedef __attribute__((ext_vector_type(4))) float f32x4;

static __device__ __forceinline__ float blo(unsigned u) {
    union { unsigned u; float f; } v; v.u = u << 16; return v.f;
}
static __device__ __forceinline__ float bhi(unsigned u) {
    union { unsigned u; float f; } v; v.u = u & 0xffff0000u; return v.f;
}
static __device__ __forceinline__ unsigned pk2(float lo, float hi) {
    __hip_bfloat162 h = __float22bfloat162_rn(float2{lo, hi});   // v_cvt_pk_bf16_f32
    union { __hip_bfloat162 h; unsigned u; } v; v.h = h; return v.u;
}
static __device__ __forceinline__ unsigned short bf1(float f) {
    __hip_bfloat16 h = __float2bfloat16(f);
    union { __hip_bfloat16 h; unsigned short u; } v; v.h = h; return v.u;
}
static __device__ __forceinline__ f32x4 red16(f32x4 v) {
#pragma unroll
    for (int m = 1; m < 16; m <<= 1) {
        v[0] += __shfl_xor(v[0], m);
        v[1] += __shfl_xor(v[1], m);
        v[2] += __shfl_xor(v[2], m);
        v[3] += __shfl_xor(v[3], m);
    }
    return v;
}

// named-member staging block: SROA-friendly (no arrays, no address-taken)
struct SG { uint4 r1, r3, r2, r4, rc; };

// ---------------- transpose + cast: x[B,C,E] f32 -> xT[B,E,C] bf16 ----------
__global__ __launch_bounds__(256) void k_transpose(const float* __restrict__ x,
                                                   unsigned short* __restrict__ xT) {
    __shared__ float tile[64][CIN + 1];
    const int t = threadIdx.x;
    const int e0 = blockIdx.x * 64;
    const int b = blockIdx.y;
    const int el = t & 63;
    const bool ok = (e0 + el) < EE;
    const float* xb = x + (size_t)b * CIN * EE;
#pragma unroll
    for (int cc = 0; cc < CIN / 4; ++cc) {
        const int c = cc * 4 + (t >> 6);
        tile[el][c] = ok ? xb[(size_t)c * EE + e0 + el] : 0.f;
    }
    __syncthreads();
    const int el2 = t >> 2, cq = t & 3;
    if (e0 + el2 < EE) {
        unsigned short* dst = xT + ((size_t)b * EE + e0 + el2) * CIN + cq * 32;
#pragma unroll
        for (int j = 0; j < 4; ++j) {
            const unsigned v0 = pk2(tile[el2][cq * 32 + 8 * j + 0], tile[el2][cq * 32 + 8 * j + 1]);
            const unsigned v1 = pk2(tile[el2][cq * 32 + 8 * j + 2], tile[el2][cq * 32 + 8 * j + 3]);
            const unsigned v2 = pk2(tile[el2][cq * 32 + 8 * j + 4], tile[el2][cq * 32 + 8 * j + 5]);
            const unsigned v3 = pk2(tile[el2][cq * 32 + 8 * j + 6], tile[el2][cq * 32 + 8 * j + 7]);
            *(uint4*)(dst + 8 * j) = make_uint4(v0, v1, v2, v3);
        }
    }
}

// ------------- W repack: W[m][c][k] f32 -> Wf[G/32][m][G%32] bf16 -----------
// K-order: G = chunk*KCH + k*BC + (c - chunk*BC), chunk = c/BC
// ss != null: fold BN scale (k<3: sc_c, else |sc_c|)
__global__ __launch_bounds__(256) void k_wprep(const float* __restrict__ W,
                                               unsigned short* __restrict__ Wf,
                                               const float* __restrict__ ss,
                                               int C, int K) {
    const int id = blockIdx.x * 256 + threadIdx.x;
    if (id >= 256 * K) return;
    const int m = id / K;
    const int G = id % K;
    const int chunk = G / KCH;
    const int r = G % KCH;
    const int k = r / BC;
    const int c = chunk * BC + (r % BC);
    float val = W[((size_t)m * C + c) * 5 + k];
    if (ss) {
        const float sc = ss[c];
        val *= (k < 3) ? sc : fabsf(sc);
    }
    Wf[((size_t)(G / 32) * 256 + m) * 32 + (G % 32)] = bf1(val);
}

// -------------------------- BN stats finalize -------------------------------
__global__ __launch_bounds__(256) void k_stats(const float* __restrict__ partials,
                                               const float* __restrict__ gamma,
                                               const float* __restrict__ beta,
                                               float* __restrict__ ss) {
    const int ch = blockIdx.x;
    const int t = threadIdx.x;
    float s = 0.f, q = 0.f;
    for (int i = t; i < NBLK; i += 256) {
        s += partials[(size_t)i * 512 + ch];
        q += partials[(size_t)i * 512 + 256 + ch];
    }
    __shared__ float ls[256], lq[256];
    ls[t] = s; lq[t] = q;
    __syncthreads();
    for (int off = 128; off > 0; off >>= 1) {
        if (t < off) { ls[t] += ls[t + off]; lq[t] += lq[t + off]; }
        __syncthreads();
    }
    if (t == 0) {
        const float inv = 1.f / (float)(BB * EE);
        const float mean = ls[0] * inv;
        const float var = lq[0] * inv - mean * mean;
        const float sc = gamma[ch] * rsqrtf(var + 1e-5f);
        ss[ch] = sc;
        ss[COUT + ch] = beta[ch] - mean * sc;
    }
}

// ---------------- bias[o] = sum_c sh_c * (W1[o,c,0] + 2W1[o,c,1] + 2W1[o,c,2])
__global__ __launch_bounds__(256) void k_bias(const float* __restrict__ W1,
                                              const float* __restrict__ ss,
                                              float* __restrict__ bias) {
    const int o = blockIdx.x, t = threadIdx.x;
    const float sh = ss[COUT + t];
    const float* wr = W1 + ((size_t)o * COUT + t) * 5;
    float v = sh * (wr[0] + 2.f * (wr[1] + wr[2]));
    __shared__ float red[256];
    red[t] = v;
    __syncthreads();
    for (int off = 128; off > 0; off >>= 1) {
        if (t < off) red[t] += red[t + off];
        __syncthreads();
    }
    if (t == 0) bias[o] = red[0];
}

// feature-pair build: sum & |diff| of two packed bf16 pairs
#define FPAIR(ua_, ub_, osum_, odif_) do {                                   \
    const float fa0_ = blo(ua_), fa1_ = bhi(ua_);                            \
    const float fb0_ = blo(ub_), fb1_ = bhi(ub_);                            \
    osum_ = pk2(fa0_ + fb0_, fa1_ + fb1_);                                   \
    odif_ = pk2(fabsf(fa0_ - fb0_), fabsf(fa1_ - fb1_));                     \
} while (0)

#define STAGE(chv_, s_) do {                                                 \
    const int cb_ = (chv_) * BC + bq * 8;                                    \
    s_.r1 = *(const uint4*)(row1 + cb_);                                     \
    s_.r3 = *(const uint4*)(row3 + cb_);                                     \
    s_.r2 = *(const uint4*)(row2 + cb_);                                     \
    s_.r4 = *(const uint4*)(row4 + cb_);                                     \
    s_.rc = *(const uint4*)(rowc + cb_);                                     \
} while (0)

// W-slot load: 2 a-frags (fm=0,1) for one kk into named slot regs
#define LDW(slot_, kk_) do {                                                 \
    wa##slot_##_0 = *(const bf16x8*)(wc + (kk_) * 8192);                     \
    wa##slot_##_1 = *(const bf16x8*)(wc + (kk_) * 8192 + 512);               \
} while (0)

// one kk step: 8 LDS b-frags (fn 0..7), 16 MFMA; split in halves for regs
#define MMK(kk_, slot_) do {                                                 \
    const bf16x8 bf0_ = *(const bf16x8*)(blp + 0 * 16 * PITCH + (kk_) * 32); \
    const bf16x8 bf1_ = *(const bf16x8*)(blp + 1 * 16 * PITCH + (kk_) * 32); \
    const bf16x8 bf2_ = *(const bf16x8*)(blp + 2 * 16 * PITCH + (kk_) * 32); \
    const bf16x8 bf3_ = *(const bf16x8*)(blp + 3 * 16 * PITCH + (kk_) * 32); \
    d00 = __builtin_amdgcn_mfma_f32_16x16x32_bf16(wa##slot_##_0, bf0_, d00, 0, 0, 0); \
    d10 = __builtin_amdgcn_mfma_f32_16x16x32_bf16(wa##slot_##_1, bf0_, d10, 0, 0, 0); \
    d01 = __builtin_amdgcn_mfma_f32_16x16x32_bf16(wa##slot_##_0, bf1_, d01, 0, 0, 0); \
    d11 = __builtin_amdgcn_mfma_f32_16x16x32_bf16(wa##slot_##_1, bf1_, d11, 0, 0, 0); \
    d02 = __builtin_amdgcn_mfma_f32_16x16x32_bf16(wa##slot_##_0, bf2_, d02, 0, 0, 0); \
    d12 = __builtin_amdgcn_mfma_f32_16x16x32_bf16(wa##slot_##_1, bf2_, d12, 0, 0, 0); \
    d03 = __builtin_amdgcn_mfma_f32_16x16x32_bf16(wa##slot_##_0, bf3_, d03, 0, 0, 0); \
    d13 = __builtin_amdgcn_mfma_f32_16x16x32_bf16(wa##slot_##_1, bf3_, d13, 0, 0, 0); \
    const bf16x8 bf4_ = *(const bf16x8*)(blp + 4 * 16 * PITCH + (kk_) * 32); \
    const bf16x8 bf5_ = *(const bf16x8*)(blp + 5 * 16 * PITCH + (kk_) * 32); \
    const bf16x8 bf6_ = *(const bf16x8*)(blp + 6 * 16 * PITCH + (kk_) * 32); \
    const bf16x8 bf7_ = *(const bf16x8*)(blp + 7 * 16 * PITCH + (kk_) * 32); \
    d04 = __builtin_amdgcn_mfma_f32_16x16x32_bf16(wa##slot_##_0, bf4_, d04, 0, 0, 0); \
    d14 = __builtin_amdgcn_mfma_f32_16x16x32_bf16(wa##slot_##_1, bf4_, d14, 0, 0, 0); \
    d05 = __builtin_amdgcn_mfma_f32_16x16x32_bf16(wa##slot_##_0, bf5_, d05, 0, 0, 0); \
    d15 = __builtin_amdgcn_mfma_f32_16x16x32_bf16(wa##slot_##_1, bf5_, d15, 0, 0, 0); \
    d06 = __builtin_amdgcn_mfma_f32_16x16x32_bf16(wa##slot_##_0, bf6_, d06, 0, 0, 0); \
    d16 = __builtin_amdgcn_mfma_f32_16x16x32_bf16(wa##slot_##_1, bf6_, d16, 0, 0, 0); \
    d07 = __builtin_amdgcn_mfma_f32_16x16x32_bf16(wa##slot_##_0, bf7_, d07, 0, 0, 0); \
    d17 = __builtin_amdgcn_mfma_f32_16x16x32_bf16(wa##slot_##_1, bf7_, d17, 0, 0, 0); \
} while (0)

// conv0 epilogue, one fragment (fm_, fn_, acc cc_)
#define EP0One(fm_, fn_, cc_, ksv_, kqv_) do {                               \
    uint2 pk_; pk_.x = pk2(cc_[0], cc_[1]); pk_.y = pk2(cc_[2], cc_[3]);     \
    *(uint2*)(x1 + (fragbase + (fm_) * 8 + (fn_)) * 256 + lane * 4) = pk_;   \
    const int e_ = e0 + (fn_) * 16 + ml;                                     \
    float r0_ = fmaxf(cc_[0], 0.f), r1_ = fmaxf(cc_[1], 0.f);                \
    float r2_ = fmaxf(cc_[2], 0.f), r3_ = fmaxf(cc_[3], 0.f);                \
    if (e_ < EE) {                                                           \
        uint2 pr_; pr_.x = pk2(r0_, r1_); pr_.y = pk2(r2_, r3_);             \
        *(uint2*)(rT + ((size_t)b * EE + e_) * COUT + w * 32 + (fm_) * 16 + g * 4) = pr_; \
    } else { r0_ = r1_ = r2_ = r3_ = 0.f; }                                  \
    ksv_[0] += r0_; kqv_[0] += r0_ * r0_; ksv_[1] += r1_; kqv_[1] += r1_ * r1_; \
    ksv_[2] += r2_; kqv_[2] += r2_ * r2_; ksv_[3] += r3_; kqv_[3] += r3_ * r3_; \
} while (0)

// conv1 epilogue, one fragment: residual add + bias + relu, f32 out
#define EP1One(fm_, fn_, cc_, bv_) do {                                      \
    const uint2 pk_ = *(const uint2*)(x1 + (fragbase + (fm_) * 8 + (fn_)) * 256 + lane * 4); \
    const int e_ = e0 + (fn_) * 16 + ml;                                     \
    if (e_ < EE) {                                                           \
        float* op_ = out + ((size_t)b * COUT + (w * 32 + (fm_) * 16 + g * 4)) * EE + e_; \
        op_[0]              = fmaxf(cc_[0] + bv_.x + blo(pk_.x), 0.f);       \
        op_[EE]             = fmaxf(cc_[1] + bv_.y + bhi(pk_.x), 0.f);       \
        op_[2 * (size_t)EE] = fmaxf(cc_[2] + bv_.z + blo(pk_.y), 0.f);       \
        op_[3 * (size_t)EE] = fmaxf(cc_[3] + bv_.w + bhi(pk_.y), 0.f);       \
    }                                                                        \
} while (0)

// --------------------------- fused mesh-conv GEMM ---------------------------
// 512 threads = 8 waves; block tile 256ch x 128e; wave tile 32ch x 128e.
// w = wch (0..7, distinct channel groups -> W loaded once per block).
template <int C, int CHUNKS, int IS1>
__global__ __launch_bounds__(512, 4) void k_conv(
    const unsigned short* __restrict__ xin,
    const int* __restrict__ gmm,
    const unsigned short* __restrict__ Wf,
    const float* __restrict__ bias,
    unsigned short* __restrict__ x1,
    unsigned short* __restrict__ rT,
    float* __restrict__ partials,
    float* __restrict__ out) {
    __shared__ unsigned short f_lds[128 * PITCH];
    const int t = threadIdx.x;
    const int w = t >> 6, lane = t & 63;
    const int ml = lane & 15, g = lane >> 4;
    // XCD batch-affinity decode: batch b -> XCDs {2b,2b+1}
    const int i = blockIdx.x;
    const int b = (i & 7) >> 1;
    const int tile = ((i >> 3) << 1) | (i & 1);
    if (tile >= NT) return;
    const int e0 = tile * BN;

    // build roles: 4 threads per edge, each owns 8 channels of each chunk
    const int be = t >> 2, bq = t & 3;
    const int eb = e0 + be;
    const int ec = (eb < EE) ? eb : 0;
    const int4 nb = *(const int4*)(gmm + ((size_t)b * EE + ec) * 4);

    const unsigned short* xb = xin + (size_t)b * EE * C;
    const unsigned short* rowc = xb + (size_t)ec * C;
    const unsigned short* row1 = xb + (size_t)nb.x * C;
    const unsigned short* row2 = xb + (size_t)nb.y * C;
    const unsigned short* row3 = xb + (size_t)nb.z * C;
    const unsigned short* row4 = xb + (size_t)nb.w * C;

    f32x4 d00 = {0,0,0,0}, d01 = {0,0,0,0}, d02 = {0,0,0,0}, d03 = {0,0,0,0};
    f32x4 d04 = {0,0,0,0}, d05 = {0,0,0,0}, d06 = {0,0,0,0}, d07 = {0,0,0,0};
    f32x4 d10 = {0,0,0,0}, d11 = {0,0,0,0}, d12 = {0,0,0,0}, d13 = {0,0,0,0};
    f32x4 d14 = {0,0,0,0}, d15 = {0,0,0,0}, d16 = {0,0,0,0}, d17 = {0,0,0,0};

    SG s;
    STAGE(0, s);

    // per-thread invariant addresses
    unsigned short* bp = &f_lds[be * PITCH + bq * 8];
    const unsigned short* wl = Wf + (size_t)(w * 32 + ml) * 32 + g * 8;  // A row base
    const unsigned short* blp = &f_lds[ml * PITCH + g * 8];              // B row base

#pragma unroll 1
    for (int chunk = 0; chunk < CHUNKS; ++chunk) {
        // ---- build symmetric features (named registers only) ----
        unsigned o1x, o1y, o1z, o1w, o3x, o3y, o3z, o3w;
        unsigned o2x, o2y, o2z, o2w, o4x, o4y, o4z, o4w;
        FPAIR(s.r1.x, s.r3.x, o1x, o3x);
        FPAIR(s.r1.y, s.r3.y, o1y, o3y);
        FPAIR(s.r1.z, s.r3.z, o1z, o3z);
        FPAIR(s.r1.w, s.r3.w, o1w, o3w);
        FPAIR(s.r2.x, s.r4.x, o2x, o4x);
        FPAIR(s.r2.y, s.r4.y, o2y, o4y);
        FPAIR(s.r2.z, s.r4.z, o2z, o4z);
        FPAIR(s.r2.w, s.r4.w, o2w, o4w);
        const uint4 ctr = s.rc;

        __syncthreads();   // previous chunk's MFMA LDS reads done (vmcnt clean)
        *(uint4*)(bp + 0 * BC) = ctr;
        *(uint4*)(bp + 1 * BC) = make_uint4(o1x, o1y, o1z, o1w);
        *(uint4*)(bp + 2 * BC) = make_uint4(o2x, o2y, o2z, o2w);
        *(uint4*)(bp + 3 * BC) = make_uint4(o3x, o3y, o3z, o3w);
        *(uint4*)(bp + 4 * BC) = make_uint4(o4x, o4y, o4z, o4w);
        __syncthreads();

        // ---- kk phase: depth-2 rotating W pipeline; gathers for chunk+1
        //      issued after the W preloads (never cross a barrier) ----
        const unsigned short* wc = wl + (size_t)chunk * 5 * 8192;
        bf16x8 wa0_0, wa0_1, wa1_0, wa1_1;
        LDW(0, 0); LDW(1, 1);
        if (chunk + 1 < CHUNKS) STAGE(chunk + 1, s);
        MMK(0, 0); LDW(0, 2);
        MMK(1, 1); LDW(1, 3);
        MMK(2, 0); LDW(0, 4);
        MMK(3, 1);
        MMK(4, 0);
    }

    // ------------------------------ epilogue --------------------------------
    const size_t fragbase = (((size_t)(b * NT + tile)) * 8 + w) * 16;
    if (!IS1) {
        f32x4 ks0 = {0,0,0,0}, kq0 = {0,0,0,0};
        f32x4 ks1 = {0,0,0,0}, kq1 = {0,0,0,0};
        EP0One(0, 0, d00, ks0, kq0);
        EP0One(0, 1, d01, ks0, kq0);
        EP0One(0, 2, d02, ks0, kq0);
        EP0One(0, 3, d03, ks0, kq0);
        EP0One(0, 4, d04, ks0, kq0);
        EP0One(0, 5, d05, ks0, kq0);
        EP0One(0, 6, d06, ks0, kq0);
        EP0One(0, 7, d07, ks0, kq0);
        EP0One(1, 0, d10, ks1, kq1);
        EP0One(1, 1, d11, ks1, kq1);
        EP0One(1, 2, d12, ks1, kq1);
        EP0One(1, 3, d13, ks1, kq1);
        EP0One(1, 4, d14, ks1, kq1);
        EP0One(1, 5, d15, ks1, kq1);
        EP0One(1, 6, d16, ks1, kq1);
        EP0One(1, 7, d17, ks1, kq1);
        ks0 = red16(ks0); kq0 = red16(kq0);
        ks1 = red16(ks1); kq1 = red16(kq1);
        if (ml == 0) {
            float* pp = partials + (size_t)(b * NT + tile) * 512;
            const int ch0 = w * 32 + g * 4;
            *(float4*)(pp + ch0)            = make_float4(ks0[0], ks0[1], ks0[2], ks0[3]);
            *(float4*)(pp + ch0 + 16)       = make_float4(ks1[0], ks1[1], ks1[2], ks1[3]);
            *(float4*)(pp + 256 + ch0)      = make_float4(kq0[0], kq0[1], kq0[2], kq0[3]);
            *(float4*)(pp + 256 + ch0 + 16) = make_float4(kq1[0], kq1[1], kq1[2], kq1[3]);
        }
    } else {
        const float4 bv0 = *(const float4*)(bias + w * 32 + g * 4);
        const float4 bv1 = *(const float4*)(bias + w * 32 + 16 + g * 4);
        EP1One(0, 0, d00, bv0);
        EP1One(0, 1, d01, bv0);
        EP1One(0, 2, d02, bv0);
        EP1One(0, 3, d03, bv0);
        EP1One(0, 4, d04, bv0);
        EP1One(0, 5, d05, bv0);
        EP1One(0, 6, d06, bv0);
        EP1One(0, 7, d07, bv0);
        EP1One(1, 0, d10, bv1);
        EP1One(1, 1, d11, bv1);
        EP1One(1, 2, d12, bv1);
        EP1One(1, 3, d13, bv1);
        EP1One(1, 4, d14, bv1);
        EP1One(1, 5, d15, bv1);
        EP1One(1, 6, d16, bv1);
        EP1One(1, 7, d17, bv1);
    }
}

extern "C" void kernel_launch(void* const* d_in, const int* in_sizes, int n_in,
                              void* d_out, int out_size, void* d_ws, size_t ws_size,
                              hipStream_t stream) {
    const float* x = (const float*)d_in[0];
    const int* gmm = (const int*)d_in[1];
    const float* W0 = (const float*)d_in[2];
    const float* gamma = (const float*)d_in[3];
    const float* beta = (const float*)d_in[4];
    const float* W1 = (const float*)d_in[5];
    float* out = (float*)d_out;

    char* ws = (char*)d_ws;
    unsigned short* xT  = (unsigned short*)(ws);
    unsigned short* Wf0 = (unsigned short*)(ws + 30720000);
    unsigned short* Wf1 = (unsigned short*)(ws + 31047680);
    unsigned short* x1  = (unsigned short*)(ws + 31703040);
    unsigned short* rT  = (unsigned short*)(ws + 93306880);
    float* partials     = (float*)(ws + 154746880);
    float* ss           = (float*)(ws + 156672000);
    float* bias         = (float*)(ws + 156674048);

    k_transpose<<<dim3(469, BB), 256, 0, stream>>>(x, xT);
    k_wprep<<<dim3(640), 256, 0, stream>>>(W0, Wf0, nullptr, CIN, 640);
    k_conv<CIN, 4, 0><<<dim3(GRID1), 512, 0, stream>>>(
        xT, gmm, Wf0, nullptr, x1, rT, partials, nullptr);
    k_stats<<<dim3(256), 256, 0, stream>>>(partials, gamma, beta, ss);
    k_bias<<<dim3(256), 256, 0, stream>>>(W1, ss, bias);
    k_wprep<<<dim3(1280), 256, 0, stream>>>(W1, Wf1, ss, COUT, 1280);
    k_conv<COUT, 8, 1><<<dim3(GRID1), 512, 0, stream>>>(
        rT, gmm, Wf1, bias, x1, nullptr, nullptr, out);
}